// Round 8
// baseline (322.645 us; speedup 1.0000x reference)
//
#include <hip/hip_runtime.h>
#include <cmath>

#define HALO 5
#define TSX 32
#define TILE_H 64
#define NCHUNK 4
#define CH 16            // output rows per chunk
#define RING 26          // H-blurred rows kept in LDS (ring buffer)
#define HSTR 36          // hb row stride (floats): 32 cols + pad
#define PLANE (RING * HSTR)
#define WIDTH 512
#define HEIGHT 512

struct GW { float g[11]; };

__device__ __forceinline__ float ssim2(float mu1, float mu2,
                                       float x2b, float y2b, float xyb)
{
    const float C1 = 1e-4f, C2 = 9e-4f;
    float mu12 = mu1 * mu2;
    float num  = (2.f * mu12 + C1) * (2.f * (xyb - mu12) + C2);
    float den  = (mu1 * mu1 + mu2 * mu2 + C1) *
                 ((x2b - mu1 * mu1) + (y2b - mu2 * mu2) + C2);
    return num * __builtin_amdgcn_rcpf(den);   // ~1 ulp; threshold is 2e-2
}

template<bool CHK>
__device__ __forceinline__ float tile_compute(
    const float* __restrict__ fI, const float* __restrict__ aI,
    const float* __restrict__ bI, float (* __restrict__ hb)[PLANE],
    const GW& gw, int tid, int x0, int y0, size_t pbase)
{
    const int rA  = tid >> 3;
    const int qA  = tid & 7;
    const int gx0 = x0 + 4 * qA - 8;     // first loaded global col (5 quads)
    const int jB  = tid & 31;
    const int rgB = tid >> 5;
    const bool actB = (rgB < 4);

    float part = 0.f;

    #pragma unroll 1
    for (int c = 0; c < NCHUNK; ++c) {
        if (c) __syncthreads();          // prev chunk's phase B done

        // ---- phase A: H-blur rows into ring slots (batched loads) ----
        const int nA = c ? CH : RING;
        if (rA < nA) {
            const int t0 = c ? (16 * c + 10 + rA) : rA;  // row rel y0-5
            int slot = t0;
            slot -= (slot >= RING) ? RING : 0;
            slot -= (slot >= RING) ? RING : 0;
            const int yy = y0 - HALO + t0;
            const bool yok = CHK ? ((unsigned)yy < (unsigned)HEIGHT) : true;
            const float* rowf = fI + pbase + (size_t)yy * WIDTH;
            const float* rowa = aI + pbase + (size_t)yy * WIDTH;
            const float* rowb = bI + pbase + (size_t)yy * WIDTH;

            float4 Lf[5], La[5], Lb[5];
            // batch 1+2: f and a rows in flight together
            #pragma unroll
            for (int k = 0; k < 5; ++k) {
                const int g = gx0 + 4 * k;
                const bool ok = CHK ? (yok && (unsigned)g <= (unsigned)(WIDTH-4)) : true;
                Lf[k] = ok ? *(const float4*)(rowf + g) : make_float4(0,0,0,0);
            }
            #pragma unroll
            for (int k = 0; k < 5; ++k) {
                const int g = gx0 + 4 * k;
                const bool ok = CHK ? (yok && (unsigned)g <= (unsigned)(WIDTH-4)) : true;
                La[k] = ok ? *(const float4*)(rowa + g) : make_float4(0,0,0,0);
            }
            // name columns (pure mem2reg, static indices; window = loaded 3..16)
            float lf[20];
            #pragma unroll
            for (int k = 0; k < 5; ++k) {
                lf[4*k+0]=Lf[k].x; lf[4*k+1]=Lf[k].y;
                lf[4*k+2]=Lf[k].z; lf[4*k+3]=Lf[k].w;
            }

            float acc[8][4];    // fields: 0=F 1=A 2=B 3=F2 4=A2 5=B2 6=FA 7=FB
            #pragma unroll
            for (int q = 0; q < 8; ++q)
                #pragma unroll
                for (int jj = 0; jj < 4; ++jj) acc[q][jj] = 0.f;

            // F pass (Lb loads issued after F-pass starts hiding under FMAs)
            #pragma unroll
            for (int k = 0; k < 5; ++k) {
                const int g = gx0 + 4 * k;
                const bool ok = CHK ? (yok && (unsigned)g <= (unsigned)(WIDTH-4)) : true;
                Lb[k] = ok ? *(const float4*)(rowb + g) : make_float4(0,0,0,0);
            }
            #pragma unroll
            for (int t = 0; t < 14; ++t) {
                const float fv = lf[t + 3];
                const float ff = fv * fv;
                #pragma unroll
                for (int jj = 0; jj < 4; ++jj) {
                    const int u = t - jj;
                    if (u >= 0 && u <= 10) {
                        const float w = gw.g[u];
                        acc[0][jj] = fmaf(w, fv, acc[0][jj]);
                        acc[3][jj] = fmaf(w, ff, acc[3][jj]);
                    }
                }
            }
            // A pass
            float la[20];
            #pragma unroll
            for (int k = 0; k < 5; ++k) {
                la[4*k+0]=La[k].x; la[4*k+1]=La[k].y;
                la[4*k+2]=La[k].z; la[4*k+3]=La[k].w;
            }
            #pragma unroll
            for (int t = 0; t < 14; ++t) {
                const float av = la[t + 3];
                const float aa = av * av;
                const float fa = lf[t + 3] * av;
                #pragma unroll
                for (int jj = 0; jj < 4; ++jj) {
                    const int u = t - jj;
                    if (u >= 0 && u <= 10) {
                        const float w = gw.g[u];
                        acc[1][jj] = fmaf(w, av, acc[1][jj]);
                        acc[4][jj] = fmaf(w, aa, acc[4][jj]);
                        acc[6][jj] = fmaf(w, fa, acc[6][jj]);
                    }
                }
            }
            // B pass
            float lb[20];
            #pragma unroll
            for (int k = 0; k < 5; ++k) {
                lb[4*k+0]=Lb[k].x; lb[4*k+1]=Lb[k].y;
                lb[4*k+2]=Lb[k].z; lb[4*k+3]=Lb[k].w;
            }
            #pragma unroll
            for (int t = 0; t < 14; ++t) {
                const float bv = lb[t + 3];
                const float bb = bv * bv;
                const float fb = lf[t + 3] * bv;
                #pragma unroll
                for (int jj = 0; jj < 4; ++jj) {
                    const int u = t - jj;
                    if (u >= 0 && u <= 10) {
                        const float w = gw.g[u];
                        acc[2][jj] = fmaf(w, bv, acc[2][jj]);
                        acc[5][jj] = fmaf(w, bb, acc[5][jj]);
                        acc[7][jj] = fmaf(w, fb, acc[7][jj]);
                    }
                }
            }
            #pragma unroll
            for (int q = 0; q < 8; ++q)
                *(float4*)(&hb[q][slot * HSTR + 4 * qA]) =
                    make_float4(acc[q][0], acc[q][1], acc[q][2], acc[q][3]);
        }
        __syncthreads();

        // ---- phase B: vertical blur, 2-deep LDS pipeline + SSIM ----
        if (actB) {
            int sb = 16 * c + 4 * rgB;
            sb -= (sb >= RING) ? RING : 0;
            sb -= (sb >= RING) ? RING : 0;
            float acc2[4][8];
            #pragma unroll
            for (int ri = 0; ri < 4; ++ri)
                #pragma unroll
                for (int q = 0; q < 8; ++q) acc2[ri][q] = 0.f;

            float hv[2][8];
            {
                const float* hp0 = &hb[0][sb * HSTR + jB];
                #pragma unroll
                for (int q = 0; q < 8; ++q) hv[0][q] = hp0[q * PLANE];
            }
            #pragma unroll
            for (int k = 0; k < 14; ++k) {
                if (k < 13) {                      // preload row k+1
                    int s = sb + k + 1;
                    s -= (s >= RING) ? RING : 0;
                    const float* hp = &hb[0][s * HSTR + jB];
                    #pragma unroll
                    for (int q = 0; q < 8; ++q) hv[(k + 1) & 1][q] = hp[q * PLANE];
                }
                #pragma unroll
                for (int ri = 0; ri < 4; ++ri) {
                    const int u = k - ri;
                    if (u >= 0 && u <= 10) {
                        const float w = gw.g[u];
                        #pragma unroll
                        for (int q = 0; q < 8; ++q)
                            acc2[ri][q] = fmaf(w, hv[k & 1][q], acc2[ri][q]);
                    }
                }
            }
            #pragma unroll
            for (int ri = 0; ri < 4; ++ri) {
                part += ssim2(acc2[ri][0], acc2[ri][1],
                              acc2[ri][3], acc2[ri][4], acc2[ri][6]);
                part += ssim2(acc2[ri][0], acc2[ri][2],
                              acc2[ri][3], acc2[ri][5], acc2[ri][7]);
            }
        }
    }
    return part;
}

__global__ __launch_bounds__(256, 5)
void ssim_tile(const float* __restrict__ fI, const float* __restrict__ aI,
               const float* __restrict__ bI, float* __restrict__ bsum,
               GW gw)
{
    __shared__ __align__(16) float hb[8][PLANE];   // 29.95 KB
    __shared__ float red[4];

    const int tid = threadIdx.x;
    const int x0 = blockIdx.x * TSX;
    const int y0 = blockIdx.y * TILE_H;
    const size_t pbase = (size_t)blockIdx.z * (size_t)(WIDTH * HEIGHT);

    const bool interior = (blockIdx.x > 0) && (blockIdx.x < gridDim.x - 1) &&
                          (blockIdx.y > 0) && (blockIdx.y < gridDim.y - 1);

    float part = interior
        ? tile_compute<false>(fI, aI, bI, hb, gw, tid, x0, y0, pbase)
        : tile_compute<true >(fI, aI, bI, hb, gw, tid, x0, y0, pbase);

    #pragma unroll
    for (int off = 32; off > 0; off >>= 1) part += __shfl_down(part, off);
    if ((tid & 63) == 0) red[tid >> 6] = part;
    __syncthreads();
    if (tid == 0) {
        int bid = blockIdx.x + gridDim.x * (blockIdx.y + gridDim.y * blockIdx.z);
        bsum[bid] = red[0] + red[1] + red[2] + red[3];
    }
}

__global__ __launch_bounds__(256)
void ssim_final(const float* __restrict__ bsum, float* __restrict__ out,
                int nb, float invTwoN)
{
    __shared__ float sred[4];
    float s = 0.f;
    for (int i = threadIdx.x; i < nb; i += 256) s += bsum[i];
    #pragma unroll
    for (int off = 32; off > 0; off >>= 1) s += __shfl_down(s, off);
    if ((threadIdx.x & 63) == 0) sred[threadIdx.x >> 6] = s;
    __syncthreads();
    if (threadIdx.x == 0)
        out[0] = 1.f - (sred[0] + sred[1] + sred[2] + sred[3]) * invTwoN;
}

extern "C" void kernel_launch(void* const* d_in, const int* in_sizes, int n_in,
                              void* d_out, int out_size, void* d_ws, size_t ws_size,
                              hipStream_t stream)
{
    const float* f  = (const float*)d_in[0];
    const float* s1 = (const float*)d_in[1];
    const float* s2 = (const float*)d_in[2];
    float* out  = (float*)d_out;
    float* bsum = (float*)d_ws;

    const int N = in_sizes[0];           // 48 * 512 * 512
    const int planes = N / (WIDTH * HEIGHT);

    GW gw;
    double gd[11], gs = 0.0;
    for (int i = 0; i < 11; ++i) {
        double d = (double)(i - 5);
        gd[i] = exp(-(d * d) / 4.5);     // 2*sigma^2 = 4.5
        gs += gd[i];
    }
    for (int i = 0; i < 11; ++i) gw.g[i] = (float)(gd[i] / gs);

    dim3 grid(WIDTH / TSX, HEIGHT / TILE_H, planes);
    const int nb = (WIDTH / TSX) * (HEIGHT / TILE_H) * planes;
    ssim_tile<<<grid, dim3(256), 0, stream>>>(f, s1, s2, bsum, gw);
    ssim_final<<<1, dim3(256), 0, stream>>>(bsum, out, nb, 0.5f / (float)N);
}

// Round 9
// 246.910 us; speedup vs baseline: 1.3067x; 1.3067x over previous
//
#include <hip/hip_runtime.h>
#include <cmath>

#define HALO 5
#define TSX 32
#define TILE_H 64
#define NCHUNK 4
#define CH 16            // output rows per chunk
#define RING 26          // H-blurred rows kept in LDS (ring buffer)
#define HSTR 36          // hb row stride (floats): 32 cols + pad
#define PLANE (RING * HSTR)
#define WIDTH 512
#define HEIGHT 512

struct GW { float g[11]; };

__device__ __forceinline__ float ssim2(float mu1, float mu2,
                                       float x2b, float y2b, float xyb)
{
    const float C1 = 1e-4f, C2 = 9e-4f;
    float mu12 = mu1 * mu2;
    float num  = (2.f * mu12 + C1) * (2.f * (xyb - mu12) + C2);
    float den  = (mu1 * mu1 + mu2 * mu2 + C1) *
                 ((x2b - mu1 * mu1) + (y2b - mu2 * mu2) + C2);
    return num * __builtin_amdgcn_rcpf(den);   // ~1 ulp; threshold is 2e-2
}

template<bool CHK>
__device__ __forceinline__ float tile_compute(
    const float* __restrict__ fI, const float* __restrict__ aI,
    const float* __restrict__ bI, float (* __restrict__ hb)[PLANE],
    const GW& gw, int tid, int x0, int y0, size_t pbase)
{
    // phase A map: (row rA, col-quad qA); phase B map: (col jB, row-quad rgB)
    const int rA  = tid >> 3;
    const int qA  = tid & 7;
    const int gx0 = x0 + 4 * qA - 8;     // first loaded global col (5 quads)
    const int jB  = tid & 31;
    const int rgB = tid >> 5;
    const bool actB = (rgB < 4);

    float part = 0.f;

    #pragma unroll 1
    for (int c = 0; c < NCHUNK; ++c) {
        if (c) __syncthreads();          // prev chunk's phase B done

        // ---- phase A: H-blur rows into ring slots ----
        const int nA = c ? CH : RING;    // chunk0: 26 rows; later: 16 new rows
        if (rA < nA) {
            const int t = c ? (16 * c + 10 + rA) : rA;  // row index rel y0-5
            int slot = t;
            slot -= (slot >= RING) ? RING : 0;
            slot -= (slot >= RING) ? RING : 0;
            const int yy = y0 - HALO + t;
            const bool yok = CHK ? ((unsigned)yy < (unsigned)HEIGHT) : true;
            const float* rowf = fI + pbase + (size_t)yy * WIDTH;
            const float* rowa = aI + pbase + (size_t)yy * WIDTH;
            const float* rowb = bI + pbase + (size_t)yy * WIDTH;

            float acc[4][8];
            #pragma unroll
            for (int jj = 0; jj < 4; ++jj)
                #pragma unroll
                for (int q = 0; q < 8; ++q) acc[jj][q] = 0.f;

            #pragma unroll
            for (int k = 0; k < 5; ++k) {
                const int g = gx0 + 4 * k;
                float4 vf, va, vb;
                if (CHK) {
                    const bool ok = yok && ((unsigned)g <= (unsigned)(WIDTH - 4));
                    vf = ok ? *(const float4*)(rowf + g) : make_float4(0,0,0,0);
                    va = ok ? *(const float4*)(rowa + g) : make_float4(0,0,0,0);
                    vb = ok ? *(const float4*)(rowb + g) : make_float4(0,0,0,0);
                } else {
                    vf = *(const float4*)(rowf + g);
                    va = *(const float4*)(rowa + g);
                    vb = *(const float4*)(rowb + g);
                }
                const float fs[4] = { vf.x, vf.y, vf.z, vf.w };
                const float as[4] = { va.x, va.y, va.z, va.w };
                const float bs[4] = { vb.x, vb.y, vb.z, vb.w };
                #pragma unroll
                for (int cc = 0; cc < 4; ++cc) {
                    const int tt = 4 * k + cc - 3;    // window col 0..13
                    if (tt < 0 || tt > 13) continue;  // static prune
                    const float f = fs[cc], a = as[cc], b = bs[cc];
                    float p[8];
                    p[0] = f; p[1] = a; p[2] = b;
                    p[3] = f * f; p[4] = a * a; p[5] = b * b;
                    p[6] = f * a; p[7] = f * b;
                    #pragma unroll
                    for (int jj = 0; jj < 4; ++jj) {
                        const int u = tt - jj;        // tap index
                        if (u >= 0 && u <= 10) {
                            const float w = gw.g[u];
                            #pragma unroll
                            for (int q = 0; q < 8; ++q)
                                acc[jj][q] = fmaf(w, p[q], acc[jj][q]);
                        }
                    }
                }
            }
            #pragma unroll
            for (int q = 0; q < 8; ++q)
                *(float4*)(&hb[q][slot * HSTR + 4 * qA]) =
                    make_float4(acc[0][q], acc[1][q], acc[2][q], acc[3][q]);
        }
        __syncthreads();

        // ---- phase B: vertical blur from ring (conflict-free b32) + SSIM ----
        if (actB) {
            int sb = 16 * c + 4 * rgB;    // first input row (rel y0-5) needed
            sb -= (sb >= RING) ? RING : 0;
            sb -= (sb >= RING) ? RING : 0;
            float acc2[4][8];
            #pragma unroll
            for (int ri = 0; ri < 4; ++ri)
                #pragma unroll
                for (int q = 0; q < 8; ++q) acc2[ri][q] = 0.f;
            #pragma unroll
            for (int k = 0; k < 14; ++k) {
                int s = sb + k;
                s -= (s >= RING) ? RING : 0;
                const float* hp = &hb[0][s * HSTR + jB];
                float hv[8];
                #pragma unroll
                for (int q = 0; q < 8; ++q) hv[q] = hp[q * PLANE];
                #pragma unroll
                for (int ri = 0; ri < 4; ++ri) {
                    const int u = k - ri;
                    if (u >= 0 && u <= 10) {
                        const float w = gw.g[u];
                        #pragma unroll
                        for (int q = 0; q < 8; ++q)
                            acc2[ri][q] = fmaf(w, hv[q], acc2[ri][q]);
                    }
                }
            }
            #pragma unroll
            for (int ri = 0; ri < 4; ++ri) {
                // fields: 0=F 1=A 2=B 3=F2 4=A2 5=B2 6=FA 7=FB
                part += ssim2(acc2[ri][0], acc2[ri][1],
                              acc2[ri][3], acc2[ri][4], acc2[ri][6]);
                part += ssim2(acc2[ri][0], acc2[ri][2],
                              acc2[ri][3], acc2[ri][5], acc2[ri][7]);
            }
        }
    }
    return part;
}

__global__ __launch_bounds__(256, 4)
void ssim_tile(const float* __restrict__ fI, const float* __restrict__ aI,
               const float* __restrict__ bI, float* __restrict__ bsum,
               GW gw)
{
    __shared__ __align__(16) float hb[8][PLANE];   // 29.95 KB
    __shared__ float red[4];

    const int tid = threadIdx.x;
    const int x0 = blockIdx.x * TSX;
    const int y0 = blockIdx.y * TILE_H;
    const size_t pbase = (size_t)blockIdx.z * (size_t)(WIDTH * HEIGHT);

    const bool interior = (blockIdx.x > 0) && (blockIdx.x < gridDim.x - 1) &&
                          (blockIdx.y > 0) && (blockIdx.y < gridDim.y - 1);

    float part = interior
        ? tile_compute<false>(fI, aI, bI, hb, gw, tid, x0, y0, pbase)
        : tile_compute<true >(fI, aI, bI, hb, gw, tid, x0, y0, pbase);

    // ---- reduction -> per-block partial (no atomics) ----
    #pragma unroll
    for (int off = 32; off > 0; off >>= 1) part += __shfl_down(part, off);
    if ((tid & 63) == 0) red[tid >> 6] = part;
    __syncthreads();
    if (tid == 0) {
        int bid = blockIdx.x + gridDim.x * (blockIdx.y + gridDim.y * blockIdx.z);
        bsum[bid] = red[0] + red[1] + red[2] + red[3];
    }
}

__global__ __launch_bounds__(256)
void ssim_final(const float* __restrict__ bsum, float* __restrict__ out,
                int nb, float invTwoN)
{
    __shared__ float sred[4];
    float s = 0.f;
    for (int i = threadIdx.x; i < nb; i += 256) s += bsum[i];
    #pragma unroll
    for (int off = 32; off > 0; off >>= 1) s += __shfl_down(s, off);
    if ((threadIdx.x & 63) == 0) sred[threadIdx.x >> 6] = s;
    __syncthreads();
    if (threadIdx.x == 0)
        out[0] = 1.f - (sred[0] + sred[1] + sred[2] + sred[3]) * invTwoN;
}

extern "C" void kernel_launch(void* const* d_in, const int* in_sizes, int n_in,
                              void* d_out, int out_size, void* d_ws, size_t ws_size,
                              hipStream_t stream)
{
    const float* f  = (const float*)d_in[0];
    const float* s1 = (const float*)d_in[1];
    const float* s2 = (const float*)d_in[2];
    float* out  = (float*)d_out;
    float* bsum = (float*)d_ws;          // 6144 floats = 24 KB scratch

    const int N = in_sizes[0];           // 48 * 512 * 512
    const int planes = N / (WIDTH * HEIGHT);

    GW gw;
    double gd[11], gs = 0.0;
    for (int i = 0; i < 11; ++i) {
        double d = (double)(i - 5);
        gd[i] = exp(-(d * d) / 4.5);     // 2*sigma^2 = 4.5
        gs += gd[i];
    }
    for (int i = 0; i < 11; ++i) gw.g[i] = (float)(gd[i] / gs);

    dim3 grid(WIDTH / TSX, HEIGHT / TILE_H, planes);
    const int nb = (WIDTH / TSX) * (HEIGHT / TILE_H) * planes;
    ssim_tile<<<grid, dim3(256), 0, stream>>>(f, s1, s2, bsum, gw);
    ssim_final<<<1, dim3(256), 0, stream>>>(bsum, out, nb, 0.5f / (float)N);
}